// Round 10
// baseline (140.648 us; speedup 1.0000x reference)
//
#include <hip/hip_runtime.h>

#define NN 128
#define CC_ 16
#define HH 32
#define WW 32
#define DD 4096   // 16*16*16 pooled features per sample
#define ND (NN*DD)

typedef float v2f __attribute__((ext_vector_type(2)));

// c = sqrt(0.5*log2(e)); folded into the means so the per-term exponent is
// exp2(-(q*q)) with the negate absorbed by the v_exp input modifier.
#define MU_SCALE 0.8493218002880191f

// ---------------------------------------------------------------------------
// Kernel 1: fused 2x2 avg-pool, interleaved layout:
//   wm[n*DD+d] = {MU_SCALE*ma, MU_SCALE*mb}, wv[n*DD+d] = {va, vb}
// Thread 0 zeroes d_out (poisoned 0xAA before every launch).
// ---------------------------------------------------------------------------
__global__ __launch_bounds__(256) void pool_kernel(
    const float* __restrict__ mu_a, const float* __restrict__ lv_a,
    const float* __restrict__ mu_b, const float* __restrict__ lv_b,
    float2* __restrict__ wm, float2* __restrict__ wv, float* __restrict__ out)
{
    int t = blockIdx.x * 256 + threadIdx.x;
    if (t == 0) out[0] = 0.0f;

    int wo = t & 15;
    int ho = (t >> 4) & 15;
    int c  = (t >> 8) & 15;
    int n  = t >> 12;

    int base = ((n * CC_ + c) * HH + 2 * ho) * WW + 2 * wo;

    float2 a0 = *(const float2*)(mu_a + base);
    float2 a1 = *(const float2*)(mu_a + base + WW);
    float2 la0 = *(const float2*)(lv_a + base);
    float2 la1 = *(const float2*)(lv_a + base + WW);
    float2 b0 = *(const float2*)(mu_b + base);
    float2 b1 = *(const float2*)(mu_b + base + WW);
    float2 lb0 = *(const float2*)(lv_b + base);
    float2 lb1 = *(const float2*)(lv_b + base + WW);

    const float ms = 0.25f * MU_SCALE;
    float ma_v = ms * (a0.x + a0.y + a1.x + a1.y);
    float mb_v = ms * (b0.x + b0.y + b1.x + b1.y);
    float va_v = 0.0625f * (__expf(la0.x) + __expf(la0.y) + __expf(la1.x) + __expf(la1.y));
    float vb_v = 0.0625f * (__expf(lb0.x) + __expf(lb0.y) + __expf(lb1.x) + __expf(lb1.y));

    wm[t] = make_float2(ma_v, mb_v);
    wv[t] = make_float2(va_v, vb_v);
}

// ---------------------------------------------------------------------------
// Kernel 2: balanced pair sums, SMALL working set (16 VGPRs of row data --
// the footprint R5 demonstrably kept resident at VGPR=32).
// Two uniform block types, both: load 8 v2f rows, then 16 j-iters of
// (2 loads + 4 packed groups). 64 packed groups / thread everywhere.
//  TRI (y<144): aa+bb, 4 i-rows x 16 j lower-triangle tile; {a,b} packed per
//    lane. Only the tj==ti>>2 tile carries the diagonal -> weights {1,.5,0}.
//  AB (y>=144): a-vs-b, 8 i-rows (2 packed per v2f) x 16 j, full matrix.
// Grid: x=16 d-chunks, y=272 -> 4352 uniform blocks (~2x resident capacity,
// dynamic rebalancing -- fixes R6 imbalance without R7/R8 register blowup).
// ---------------------------------------------------------------------------
__device__ __forceinline__ void pair_group(
    v2f& acc, v2f mi, v2f mj, v2f vi, v2f vj)
{
    v2f dd = mi - mj;          // v_pk_add
    v2f s  = vi + vj;          // v_pk_add
    v2f r;
    r.x = __builtin_amdgcn_rsqf(s.x);
    r.y = __builtin_amdgcn_rsqf(s.y);
    v2f q  = dd * r;           // v_pk_mul
    v2f qq = q * q;            // v_pk_mul
    v2f e;
    e.x = __builtin_amdgcn_exp2f(-qq.x);
    e.y = __builtin_amdgcn_exp2f(-qq.y);
    acc += e * r;              // v_pk_fma
}

__device__ __forceinline__ void pair_group_w(
    v2f& acc, float w, v2f mi, v2f mj, v2f vi, v2f vj)
{
    v2f dd = mi - mj;
    v2f s  = vi + vj;
    v2f r;
    r.x = __builtin_amdgcn_rsqf(s.x);
    r.y = __builtin_amdgcn_rsqf(s.y);
    v2f q  = dd * r;
    v2f qq = q * q;
    v2f e;
    e.x = __builtin_amdgcn_exp2f(-qq.x);
    e.y = __builtin_amdgcn_exp2f(-qq.y);
    v2f er = e * r;
    acc += (v2f){w, w} * er;
}

__global__ __launch_bounds__(256) void pair_kernel(
    const float2* __restrict__ wm, const float2* __restrict__ wv,
    float* __restrict__ out)
{
    const int d = blockIdx.x * 256 + threadIdx.x;
    const int y = blockIdx.y;

    float part;

    if (y < 144) {
        // ---- TRI: aa+bb, 4 i-rows x 16 j of the lower triangle ----
        // ti grouped by 4 (g = ti>>2): tiles before group g = 2g(g+1).
        int g = (int)((sqrtf(2.0f * (float)y + 1.0f) - 1.0f) * 0.5f);
        while (2 * (g + 1) * (g + 2) <= y) ++g;
        while (2 * g * (g + 1) > y) --g;
        int rem = y - 2 * g * (g + 1);
        int ti = 4 * g + rem / (g + 1);
        int tj = rem % (g + 1);
        const int i0 = ti * 4, j0 = tj * 16;
        const bool has_diag = (tj == (ti >> 2));

        v2f pm[4], pv[4];
#pragma unroll
        for (int p = 0; p < 4; ++p) {
            float2 m = wm[(i0 + p) * DD + d];
            float2 v = wv[(i0 + p) * DD + d];
            pm[p] = (v2f){m.x, m.y};
            pv[p] = (v2f){v.x, v.y};
        }

        v2f acc0 = (v2f){0.0f, 0.0f};
        v2f acc1 = (v2f){0.0f, 0.0f};
        if (!has_diag) {
#pragma unroll 4
            for (int jj = 0; jj < 16; ++jj) {
                float2 mjf = wm[(j0 + jj) * DD + d];
                float2 vjf = wv[(j0 + jj) * DD + d];
                v2f mj = (v2f){mjf.x, mjf.y};
                v2f vj = (v2f){vjf.x, vjf.y};
                pair_group(acc0, pm[0], mj, pv[0], vj);
                pair_group(acc1, pm[1], mj, pv[1], vj);
                pair_group(acc0, pm[2], mj, pv[2], vj);
                pair_group(acc1, pm[3], mj, pv[3], vj);
            }
        } else {
#pragma unroll 4
            for (int jj = 0; jj < 16; ++jj) {
                float2 mjf = wm[(j0 + jj) * DD + d];
                float2 vjf = wv[(j0 + jj) * DD + d];
                v2f mj = (v2f){mjf.x, mjf.y};
                v2f vj = (v2f){vjf.x, vjf.y};
                int j = j0 + jj;
#pragma unroll
                for (int p = 0; p < 4; ++p) {
                    int i = i0 + p;
                    float w = (j < i) ? 1.0f : ((j == i) ? 0.5f : 0.0f);
                    pair_group_w((p & 1) ? acc1 : acc0, w, pm[p], mj, pv[p], vj);
                }
            }
        }
        v2f acc = acc0 + acc1;
        part = 2.0f * (acc.x + acc.y);
    } else {
        // ---- AB: a-vs-b, 8 i-rows (packed 2/v2f) x 16 j, full matrix ----
        const int y2 = y - 144;
        const int i0 = (y2 >> 3) * 8;
        const int j0 = (y2 & 7) * 16;

        v2f pma[4], pva[4];
#pragma unroll
        for (int p = 0; p < 4; ++p) {
            float2 m0 = wm[(i0 + 2 * p) * DD + d];
            float2 m1 = wm[(i0 + 2 * p + 1) * DD + d];
            float2 v0 = wv[(i0 + 2 * p) * DD + d];
            float2 v1 = wv[(i0 + 2 * p + 1) * DD + d];
            pma[p] = (v2f){m0.x, m1.x};
            pva[p] = (v2f){v0.x, v1.x};
        }

        v2f acc0 = (v2f){0.0f, 0.0f};
        v2f acc1 = (v2f){0.0f, 0.0f};
#pragma unroll 4
        for (int jj = 0; jj < 16; ++jj) {
            float2 jm = wm[(j0 + jj) * DD + d];
            float2 jv = wv[(j0 + jj) * DD + d];
            v2f jmb2 = (v2f){jm.y, jm.y};
            v2f jvb2 = (v2f){jv.y, jv.y};
            pair_group(acc0, pma[0], jmb2, pva[0], jvb2);
            pair_group(acc1, pma[1], jmb2, pva[1], jvb2);
            pair_group(acc0, pma[2], jmb2, pva[2], jvb2);
            pair_group(acc1, pma[3], jmb2, pva[3], jvb2);
        }
        v2f acc = acc0 + acc1;
        part = -2.0f * (acc.x + acc.y);
    }

    // wave (64-lane) shuffle reduction
#pragma unroll
    for (int off = 32; off > 0; off >>= 1)
        part += __shfl_down(part, off, 64);

    __shared__ float wsum[4];
    int lane = threadIdx.x & 63;
    int wv_  = threadIdx.x >> 6;
    if (lane == 0) wsum[wv_] = part;
    __syncthreads();
    if (threadIdx.x == 0) {
        float s = wsum[0] + wsum[1] + wsum[2] + wsum[3];
        atomicAdd(out, s);
    }
}

extern "C" void kernel_launch(void* const* d_in, const int* in_sizes, int n_in,
                              void* d_out, int out_size, void* d_ws, size_t ws_size,
                              hipStream_t stream) {
    const float* mu_a = (const float*)d_in[0];
    const float* lv_a = (const float*)d_in[1];
    const float* mu_b = (const float*)d_in[2];
    const float* lv_b = (const float*)d_in[3];
    float* out = (float*)d_out;
    float2* wm = (float2*)d_ws;            // ND float2 = 4 MB
    float2* wv = ((float2*)d_ws) + ND;     // ND float2 = 4 MB

    pool_kernel<<<dim3(ND / 256), 256, 0, stream>>>(mu_a, lv_a, mu_b, lv_b, wm, wv, out);
    pair_kernel<<<dim3(DD / 256, 144 + 128), 256, 0, stream>>>(wm, wv, out);
}

// Round 11
// 114.317 us; speedup vs baseline: 1.2303x; 1.2303x over previous
//
#include <hip/hip_runtime.h>

#define NN 128
#define CC_ 16
#define HH 32
#define WW 32
#define DD 4096   // 16*16*16 pooled features per sample
#define ND (NN*DD)

typedef float v2f __attribute__((ext_vector_type(2)));

// c = sqrt(0.5*log2(e)); folded into the means so the per-term exponent is
// exp2(-(q*q)) with the negate absorbed by the v_exp input modifier.
#define MU_SCALE 0.8493218002880191f

// ---------------------------------------------------------------------------
// Kernel 1: fused 2x2 avg-pool, interleaved layout:
//   wm[n*DD+d] = {MU_SCALE*ma, MU_SCALE*mb}, wv[n*DD+d] = {va, vb}
// Thread 0 zeroes d_out (poisoned 0xAA before every launch).
// ---------------------------------------------------------------------------
__global__ __launch_bounds__(256) void pool_kernel(
    const float* __restrict__ mu_a, const float* __restrict__ lv_a,
    const float* __restrict__ mu_b, const float* __restrict__ lv_b,
    float2* __restrict__ wm, float2* __restrict__ wv, float* __restrict__ out)
{
    int t = blockIdx.x * 256 + threadIdx.x;
    if (t == 0) out[0] = 0.0f;

    int wo = t & 15;
    int ho = (t >> 4) & 15;
    int c  = (t >> 8) & 15;
    int n  = t >> 12;

    int base = ((n * CC_ + c) * HH + 2 * ho) * WW + 2 * wo;

    float2 a0 = *(const float2*)(mu_a + base);
    float2 a1 = *(const float2*)(mu_a + base + WW);
    float2 la0 = *(const float2*)(lv_a + base);
    float2 la1 = *(const float2*)(lv_a + base + WW);
    float2 b0 = *(const float2*)(mu_b + base);
    float2 b1 = *(const float2*)(mu_b + base + WW);
    float2 lb0 = *(const float2*)(lv_b + base);
    float2 lb1 = *(const float2*)(lv_b + base + WW);

    const float ms = 0.25f * MU_SCALE;
    float ma_v = ms * (a0.x + a0.y + a1.x + a1.y);
    float mb_v = ms * (b0.x + b0.y + b1.x + b1.y);
    float va_v = 0.0625f * (__expf(la0.x) + __expf(la0.y) + __expf(la1.x) + __expf(la1.y));
    float vb_v = 0.0625f * (__expf(lb0.x) + __expf(lb0.y) + __expf(lb1.x) + __expf(lb1.y));

    wm[t] = make_float2(ma_v, mb_v);
    wv[t] = make_float2(va_v, vb_v);
}

// ---------------------------------------------------------------------------
// Kernel 2: triangle-symmetric pair sums (R6 structure: 4 i-rows, 3-range
// j-loop with half-weights {1,.5,0}) + STATIC LOAD BALANCE: each block
// processes its i-tile against the COMPLEMENTARY j-chunk pair (c, 7-c) of
// 16 j's each. One chunk is (mostly) below-diagonal (6 groups/j), the other
// (mostly) above (2 groups/j) -> ~128 groups/block nearly uniform, vs R6's
// 64..192 static spread that left CUs idle (all 2048 blocks co-resident,
// no dynamic rebalancing). Body stays 32 j-iters (R7-R10 lesson: small
// blocks drown in per-block overhead). Grid: x=16 d-chunks, y=128.
// ---------------------------------------------------------------------------
__device__ __forceinline__ void pair_group(
    v2f& acc, v2f mi, v2f mj, v2f vi, v2f vj)
{
    v2f dd = mi - mj;          // v_pk_add
    v2f s  = vi + vj;          // v_pk_add
    v2f r;
    r.x = __builtin_amdgcn_rsqf(s.x);
    r.y = __builtin_amdgcn_rsqf(s.y);
    v2f q  = dd * r;           // v_pk_mul
    v2f qq = q * q;            // v_pk_mul
    v2f e;
    e.x = __builtin_amdgcn_exp2f(-qq.x);
    e.y = __builtin_amdgcn_exp2f(-qq.y);
    acc += e * r;              // v_pk_fma
}

__device__ __forceinline__ void pair_group_w(
    v2f& acc, v2f w, v2f mi, v2f mj, v2f vi, v2f vj)
{
    v2f dd = mi - mj;
    v2f s  = vi + vj;
    v2f r;
    r.x = __builtin_amdgcn_rsqf(s.x);
    r.y = __builtin_amdgcn_rsqf(s.y);
    v2f q  = dd * r;
    v2f qq = q * q;
    v2f e;
    e.x = __builtin_amdgcn_exp2f(-qq.x);
    e.y = __builtin_amdgcn_exp2f(-qq.y);
    v2f er = e * r;
    acc += w * er;
}

// Process j in [jlo, jhi) against rows i0..i0+3 (3-range triangle split).
__device__ __forceinline__ void run_range(
    int jlo, int jhi, int i0, int d,
    const float2* __restrict__ wm, const float2* __restrict__ wv,
    v2f& acc_aa, v2f& acc_bb, v2f& acc_ab,
    const v2f pma[2], const v2f pmb[2], const v2f pva[2], const v2f pvb[2])
{
    const int below_end = min(jhi, i0);
    const int band_lo   = max(jlo, i0);
    const int band_hi   = min(jhi, i0 + 4);
    const int above_lo  = max(jlo, i0 + 4);

    // --- below diagonal: full aa + bb + ab ---
#pragma unroll 2
    for (int j = jlo; j < below_end; ++j) {
        float2 jm = wm[j * DD + d];
        float2 jv = wv[j * DD + d];
        v2f jma2 = (v2f){jm.x, jm.x};
        v2f jmb2 = (v2f){jm.y, jm.y};
        v2f jva2 = (v2f){jv.x, jv.x};
        v2f jvb2 = (v2f){jv.y, jv.y};
#pragma unroll
        for (int p = 0; p < 2; ++p) {
            pair_group(acc_aa, pma[p], jma2, pva[p], jva2);
            pair_group(acc_bb, pmb[p], jmb2, pvb[p], jvb2);
            pair_group(acc_ab, pma[p], jmb2, pva[p], jvb2);
        }
    }

    // --- diagonal band (<=4 iters): per-row half-weights {1, .5, 0} ---
    for (int j = band_lo; j < band_hi; ++j) {
        float2 jm = wm[j * DD + d];
        float2 jv = wv[j * DD + d];
        v2f jma2 = (v2f){jm.x, jm.x};
        v2f jmb2 = (v2f){jm.y, jm.y};
        v2f jva2 = (v2f){jv.x, jv.x};
        v2f jvb2 = (v2f){jv.y, jv.y};
        v2f w[2];
#pragma unroll
        for (int p = 0; p < 2; ++p) {
            int r0 = i0 + 2 * p, r1 = r0 + 1;
            w[p].x = (j < r0) ? 1.0f : (j == r0 ? 0.5f : 0.0f);
            w[p].y = (j < r1) ? 1.0f : (j == r1 ? 0.5f : 0.0f);
        }
#pragma unroll
        for (int p = 0; p < 2; ++p) {
            pair_group_w(acc_aa, w[p], pma[p], jma2, pva[p], jva2);
            pair_group_w(acc_bb, w[p], pmb[p], jmb2, pvb[p], jvb2);
            pair_group(acc_ab, pma[p], jmb2, pva[p], jvb2);
        }
    }

    // --- above diagonal: ab only ---
#pragma unroll 2
    for (int j = above_lo; j < jhi; ++j) {
        float2 jm = wm[j * DD + d];
        float2 jv = wv[j * DD + d];
        v2f jmb2 = (v2f){jm.y, jm.y};
        v2f jvb2 = (v2f){jv.y, jv.y};
#pragma unroll
        for (int p = 0; p < 2; ++p) {
            pair_group(acc_ab, pma[p], jmb2, pva[p], jvb2);
        }
    }
}

__global__ __launch_bounds__(256) void pair_kernel(
    const float2* __restrict__ wm, const float2* __restrict__ wv,
    float* __restrict__ out)
{
    const int d  = blockIdx.x * 256 + threadIdx.x;
    const int ti = blockIdx.y >> 2;        // 0..31
    const int pp = blockIdx.y & 3;         // pair index 0..3
    const int i0 = ti * 4;
    const int c0 = pp;                     // chunk c0 and its complement 7-c0
    const int c1 = 7 - pp;

    // Load 4 i-rows, repack by tensor (16 VGPRs of row data).
    v2f pma[2], pmb[2], pva[2], pvb[2];
#pragma unroll
    for (int p = 0; p < 2; ++p) {
        float2 m0 = wm[(i0 + 2 * p) * DD + d];
        float2 m1 = wm[(i0 + 2 * p + 1) * DD + d];
        float2 v0 = wv[(i0 + 2 * p) * DD + d];
        float2 v1 = wv[(i0 + 2 * p + 1) * DD + d];
        pma[p] = (v2f){m0.x, m1.x};
        pmb[p] = (v2f){m0.y, m1.y};
        pva[p] = (v2f){v0.x, v1.x};
        pvb[p] = (v2f){v0.y, v1.y};
    }

    v2f acc_aa = (v2f){0.0f, 0.0f};
    v2f acc_bb = (v2f){0.0f, 0.0f};
    v2f acc_ab = (v2f){0.0f, 0.0f};

    run_range(c0 * 16, c0 * 16 + 16, i0, d, wm, wv,
              acc_aa, acc_bb, acc_ab, pma, pmb, pva, pvb);
    run_range(c1 * 16, c1 * 16 + 16, i0, d, wm, wv,
              acc_aa, acc_bb, acc_ab, pma, pmb, pva, pvb);

    // vaa + vbb - 2 vab = 2 * (half_aa + half_bb - half_ab)
    float part = 2.0f * ((acc_aa.x + acc_aa.y) + (acc_bb.x + acc_bb.y)
                       - (acc_ab.x + acc_ab.y));

    // wave (64-lane) shuffle reduction
#pragma unroll
    for (int off = 32; off > 0; off >>= 1)
        part += __shfl_down(part, off, 64);

    __shared__ float wsum[4];
    int lane = threadIdx.x & 63;
    int wv_  = threadIdx.x >> 6;
    if (lane == 0) wsum[wv_] = part;
    __syncthreads();
    if (threadIdx.x == 0) {
        float s = wsum[0] + wsum[1] + wsum[2] + wsum[3];
        atomicAdd(out, s);
    }
}

extern "C" void kernel_launch(void* const* d_in, const int* in_sizes, int n_in,
                              void* d_out, int out_size, void* d_ws, size_t ws_size,
                              hipStream_t stream) {
    const float* mu_a = (const float*)d_in[0];
    const float* lv_a = (const float*)d_in[1];
    const float* mu_b = (const float*)d_in[2];
    const float* lv_b = (const float*)d_in[3];
    float* out = (float*)d_out;
    float2* wm = (float2*)d_ws;            // ND float2 = 4 MB
    float2* wv = ((float2*)d_ws) + ND;     // ND float2 = 4 MB

    pool_kernel<<<dim3(ND / 256), 256, 0, stream>>>(mu_a, lv_a, mu_b, lv_b, wm, wv, out);
    pair_kernel<<<dim3(DD / 256, 128), 256, 0, stream>>>(wm, wv, out);
}